// Round 14
// baseline (79.088 us; speedup 1.0000x reference)
//
#include <hip/hip_runtime.h>
#include <hip/hip_bf16.h>

#define KDIM 1000
#define KPAD 1024
#define DDIM 2048
#define BDIM 8192
#define TINV 0.25f   // 1/T, T=4
#define KSPLIT 2     // k_gram K-split factor (K=1024 per block, 4 chunks of 256)
#define REP_LOSS 5   // instrumentation: k_loss amplified (rotated rows, idempotent)

typedef __attribute__((ext_vector_type(8))) short bf16x8;
typedef __attribute__((ext_vector_type(4))) float f32x4;
typedef __attribute__((ext_vector_type(4))) unsigned short u16x4;

__device__ inline float wred_sum(float v){
  #pragma unroll
  for (int m = 32; m; m >>= 1) v += __shfl_xor(v, m, 64);
  return v;
}
__device__ inline unsigned short f2bf_rne(float f){
  unsigned u = __float_as_uint(f);
  return (unsigned short)((u + 0x7FFFu + ((u >> 16) & 1u)) >> 16);
}
__device__ inline float bf2f(unsigned short h){
  return __uint_as_float(((unsigned)h) << 16);
}
__device__ inline void gload16(const void* g, void* l){
  __builtin_amdgcn_global_load_lds(
      (const __attribute__((address_space(1))) void*)g,
      (__attribute__((address_space(3))) void*)l, 16, 0, 0);
}

// ws layout (bytes):
//   [256 .. )      : Wb bf16 [KPAD][DDIM]             (4 MB)
//   [+4MB .. )     : Gp f32 [KSPLIT][KPAD][KPAD]      (8 MB)
//   [+12MB .. )    : TSb bf16 [KDIM][KPAD]            (2 MB)
//   [+14MB .. )    : partials f32 [BDIM]              (32 KB)

// Kernel 1: f32 -> bf16 convert (rows >= KDIM zero-padded).  [R11-verbatim]
__global__ __launch_bounds__(256) void k_convert(const float* __restrict__ W,
                                                 short* __restrict__ Wb){
  int gid  = blockIdx.x * 256 + threadIdx.x;
  int base = gid * 8;
  int row  = base >> 11;
  bf16x8 v;
  if (row < KDIM) {
    const float* src = W + base;
    #pragma unroll
    for (int i = 0; i < 8; i++) v[i] = (short)f2bf_rne(src[i]);
  } else {
    #pragma unroll
    for (int i = 0; i < 8; i++) v[i] = 0;
  }
  *(bf16x8*)(Wb + base) = v;
}

// Kernel 2: Gram, LDS-staged, triangular, KSPLIT=2, in-block K-loop. [R11-verbatim]
__global__ __launch_bounds__(256) void k_gram(const short* __restrict__ Wb,
                                              float* __restrict__ Gp){
  __shared__ short As[64 * 256];
  __shared__ short Bs[64 * 256];
  int tid = threadIdx.x, lane = tid & 63, w = tid >> 6;

  int t = blockIdx.x, bx = 0;
  while (t >= 16 - bx){ t -= 16 - bx; bx++; }
  int by = bx + t;
  int z  = blockIdx.y;
  const int ibase = bx * 64, jbase = by * 64;
  const bool diag = (bx == by);

  int rhalf = lane >> 5;
  int slot  = lane & 31;
  int r  = lane & 15, kg = lane >> 4;
  int ra = (w >> 1) * 32 + r;
  int rb = (w & 1) * 32 + r;
  const short* Bp = diag ? As : Bs;

  f32x4 c00 = {0,0,0,0}, c01 = {0,0,0,0}, c10 = {0,0,0,0}, c11 = {0,0,0,0};

  for (int dc = 0; dc < 4; ++dc){
    const int Kc = z * (DDIM / KSPLIT) + dc * 256;
    if (dc) __syncthreads();
    #pragma unroll
    for (int c = 0; c < 8; ++c){
      int q    = w * 8 + c;
      int row  = 2 * q + rhalf;
      int scol = (slot ^ (row & 7)) * 8;
      gload16(Wb + (size_t)(ibase + row) * DDIM + Kc + scol, As + q * 512);
      if (!diag)
        gload16(Wb + (size_t)(jbase + row) * DDIM + Kc + scol, Bs + q * 512);
    }
    __syncthreads();

    #pragma unroll
    for (int ds = 0; ds < 8; ++ds){
      int sa = ((ds * 4 + kg) ^ (ra & 7)) * 16;
      int sb = ((ds * 4 + kg) ^ (rb & 7)) * 16;
      bf16x8 a0 = *(const bf16x8*)((const char*)As + ra * 512 + sa);
      bf16x8 a1 = *(const bf16x8*)((const char*)As + (ra + 16) * 512 + sa);
      bf16x8 b0 = *(const bf16x8*)((const char*)Bp + rb * 512 + sb);
      bf16x8 b1 = *(const bf16x8*)((const char*)Bp + (rb + 16) * 512 + sb);
      c00 = __builtin_amdgcn_mfma_f32_16x16x32_bf16(a0, b0, c00, 0, 0, 0);
      c01 = __builtin_amdgcn_mfma_f32_16x16x32_bf16(a0, b1, c01, 0, 0, 0);
      c10 = __builtin_amdgcn_mfma_f32_16x16x32_bf16(a1, b0, c10, 0, 0, 0);
      c11 = __builtin_amdgcn_mfma_f32_16x16x32_bf16(a1, b1, c11, 0, 0, 0);
    }
  }

  int orow = (lane >> 4) * 4, ocol = lane & 15;
  int i0 = ibase + (w >> 1) * 32, j0 = jbase + (w & 1) * 32;
  float* Gz = Gp + ((size_t)z << 20);
  float* g  = Gz + (size_t)(i0 + orow) * KPAD + (j0 + ocol);
  #pragma unroll
  for (int rr = 0; rr < 4; rr++){
    g[(size_t)rr * KPAD]             = c00[rr];
    g[(size_t)rr * KPAD + 16]        = c01[rr];
    g[(size_t)(rr + 16) * KPAD]      = c10[rr];
    g[(size_t)(rr + 16) * KPAD + 16] = c11[rr];
  }
  if (!diag){
    float* gt = Gz + (size_t)(j0 + ocol) * KPAD + (i0 + orow);
    *(f32x4*)gt                            = c00;
    *(f32x4*)(gt + 16)                     = c10;
    *(f32x4*)(gt + (size_t)16 * KPAD)      = c01;
    *(f32x4*)(gt + (size_t)16 * KPAD + 16) = c11;
  }
}

// Kernel 3: TSb[l,:] = bf16(softmax(relu(sum_z Gp[z][l,:])^0.3 / 0.3)). [R11-verbatim]
__global__ __launch_bounds__(256) void k_ts(const float* __restrict__ Gp,
                                            unsigned short* __restrict__ TSb){
  int l = blockIdx.x;
  int t = threadIdx.x;
  int lane = t & 63, w = t >> 6;
  f32x4 g = *((const f32x4*)(Gp + (size_t)l * KPAD) + t)
          + *((const f32x4*)(Gp + (1ull << 20) + (size_t)l * KPAD) + t);
  f32x4 e;
  float s = 0.f;
  #pragma unroll
  for (int c = 0; c < 4; c++){
    int k = t * 4 + c;
    float gg = g[c];
    float zv = (gg > 0.f) ? __expf(0.3f * __logf(gg)) * (1.0f / 0.3f) : 0.f;
    float ee = (k < KDIM) ? __expf(zv) : 0.f;
    e[c] = ee;
    s += ee;
  }
  s = wred_sum(s);
  __shared__ float ps[4];
  if (lane == 0) ps[w] = s;
  __syncthreads();
  float inv = 1.0f / (ps[0] + ps[1] + ps[2] + ps[3]);
  u16x4 o;
  #pragma unroll
  for (int c = 0; c < 4; c++) o[c] = f2bf_rne(e[c] * inv);
  *(u16x4*)(TSb + (size_t)l * KPAD + t * 4) = o;
}

// Kernel 4: per-row loss, 2 waves per row, LDS combine. AMPLIFIED x5 (rotated b).
__global__ __launch_bounds__(256) void k_loss(const float* __restrict__ pred,
                                              const float* __restrict__ teacher,
                                              const int* __restrict__ label,
                                              const unsigned short* __restrict__ TSb,
                                              float* __restrict__ partials){
  int tid = threadIdx.x;
  int lane = tid & 63;
  int wv   = tid >> 6;
  int rib  = wv >> 1;
  int h    = wv & 1;
  __shared__ float s_sp[4], s_st[4], s_yl[2], s_S[4];
  for (int rep = 0; rep < REP_LOSS; ++rep){
    int b = ((blockIdx.x * 2 + rib) + rep * 2048) & (BDIM - 1);
    int l = label[b];
    const int base4 = h * 125;
    const u16x4* tsr = (const u16x4*)(TSb + (size_t)l * KPAD) + base4;
    const f32x4* pr  = (const f32x4*)(pred    + (size_t)b * KDIM) + base4;
    const f32x4* th  = (const f32x4*)(teacher + (size_t)b * KDIM) + base4;

    u16x4 ts[2];
    f32x4 x[2], y[2];
    #pragma unroll
    for (int j = 0; j < 2; j++){
      int idx = lane + 64 * j;
      bool v = (idx < 125);
      f32x4 neg = {-4e30f, -4e30f, -4e30f, -4e30f};
      ts[j]   = v ? tsr[idx] : (u16x4){0,0,0,0};
      f32x4 p = v ? pr[idx]  : neg;
      f32x4 t = v ? th[idx]  : neg;
      x[j] = p * TINV;
      y[j] = t * TINV;
    }
    float sp = 0.f, st = 0.f;
    #pragma unroll
    for (int j = 0; j < 2; j++)
      #pragma unroll
      for (int c = 0; c < 4; c++){
        sp += __expf(x[j][c]);
        st += __expf(y[j][c]);
      }
    sp = wred_sum(sp); st = wred_sum(st);

    if (lane == 0){ s_sp[wv] = sp; s_st[wv] = st; }
    int l4 = l >> 2;
    if (l4 >= base4 && l4 < base4 + 125){
      int rel = l4 - base4;
      int jl = rel >> 6, lanel = rel & 63, cl = l & 3;
      f32x4 yj   = jl ? y[1] : y[0];
      float cand = (cl == 0) ? yj[0] : (cl == 1) ? yj[1] : (cl == 2) ? yj[2] : yj[3];
      float yl   = __shfl(cand, lanel, 64);
      if (lane == 0) s_yl[rib] = yl;
    }
    __syncthreads();
    float spF = s_sp[rib * 2] + s_sp[rib * 2 + 1];
    float stF = s_st[rib * 2] + s_st[rib * 2 + 1];
    float lse_p = __logf(spF);
    float lse_t = __logf(stF);
    float conf  = __expf(s_yl[rib] - lse_t);
    float u = (1.f - conf) * (1.f / 999.f);

    float S = 0.f;
    #pragma unroll
    for (int j = 0; j < 2; j++){
      int idx = lane + 64 * j;
      if (idx < 125){
        #pragma unroll
        for (int c = 0; c < 4; c++){
          int k = (base4 + idx) * 4 + c;
          float t = 0.5f * (((k == l) ? conf : u) + bf2f(ts[j][c]));
          S += t * (__logf(t) - x[j][c]);
        }
      }
    }
    S = wred_sum(S);
    if (lane == 0) s_S[wv] = S;
    __syncthreads();
    if (h == 0 && lane == 0)
      partials[b] = s_S[rib * 2] + s_S[rib * 2 + 1] + lse_p;
    __syncthreads();                 // protect shared reuse across reps
  }
}

// Kernel 5: reduce 8192 partials, scale. 1 block, 256 threads. [R11-verbatim]
__global__ __launch_bounds__(256) void k_fin(const float* __restrict__ partials,
                                             float* __restrict__ out){
  int t = threadIdx.x;
  float s = 0.f;
  #pragma unroll 8
  for (int i = t; i < BDIM; i += 256) s += partials[i];
  s = wred_sum(s);
  __shared__ float ps[4];
  if ((t & 63) == 0) ps[t >> 6] = s;
  __syncthreads();
  if (t == 0) out[0] = (ps[0] + ps[1] + ps[2] + ps[3]) * (16.0f / 8192.0f);
}

extern "C" void kernel_launch(void* const* d_in, const int* in_sizes, int n_in,
                              void* d_out, int out_size, void* d_ws, size_t ws_size,
                              hipStream_t stream) {
  const float* pred    = (const float*)d_in[0];
  const float* teacher = (const float*)d_in[1];
  const float* weight  = (const float*)d_in[2];
  const int*   label   = (const int*)d_in[3];
  float* out = (float*)d_out;

  char* ws = (char*)d_ws;
  short*          Wb       = (short*)(ws + 256);
  float*          Gp       = (float*)(ws + 256 + (size_t)KPAD * DDIM * 2);
  unsigned short* TSb      = (unsigned short*)(ws + 256 + (size_t)KPAD * DDIM * 2
                                                  + (size_t)KSPLIT * KPAD * KPAD * 4);
  float*          partials = (float*)((char*)TSb + (size_t)KDIM * KPAD * 2);

  k_convert<<<dim3((KPAD * DDIM / 8) / 256), dim3(256), 0, stream>>>(weight, Wb);
  k_gram<<<dim3(136, KSPLIT), dim3(256), 0, stream>>>(Wb, Gp);
  k_ts<<<dim3(KDIM), dim3(256), 0, stream>>>(Gp, TSb);
  k_loss<<<dim3(BDIM / 2), dim3(256), 0, stream>>>(pred, teacher, label, TSb, partials);
  k_fin<<<dim3(1), dim3(256), 0, stream>>>(partials, out);
}

// Round 15
// 43.963 us; speedup vs baseline: 1.7990x; 1.7990x over previous
//
#include <hip/hip_runtime.h>
#include <hip/hip_bf16.h>

#define KDIM 1000
#define KPAD 1024
#define DDIM 2048
#define BDIM 8192
#define TINV 0.25f   // 1/T, T=4
#define KSPLIT 2     // k_gram K-split factor (K=1024 per block, 8 chunks of 128)

typedef __attribute__((ext_vector_type(8))) short bf16x8;
typedef __attribute__((ext_vector_type(4))) float f32x4;
typedef __attribute__((ext_vector_type(4))) unsigned short u16x4;

__device__ inline float wred_sum(float v){
  #pragma unroll
  for (int m = 32; m; m >>= 1) v += __shfl_xor(v, m, 64);
  return v;
}
__device__ inline unsigned short f2bf_rne(float f){
  unsigned u = __float_as_uint(f);
  return (unsigned short)((u + 0x7FFFu + ((u >> 16) & 1u)) >> 16);
}
__device__ inline float bf2f(unsigned short h){
  return __uint_as_float(((unsigned)h) << 16);
}
__device__ inline void gload16(const void* g, void* l){
  __builtin_amdgcn_global_load_lds(
      (const __attribute__((address_space(1))) void*)g,
      (__attribute__((address_space(3))) void*)l, 16, 0, 0);
}

// ws layout (bytes):
//   [256 .. )      : Wb bf16 [KPAD][DDIM]             (4 MB)
//   [+4MB .. )     : Gp f32 [KSPLIT][KPAD][KPAD]      (8 MB)
//   [+12MB .. )    : TSb bf16 [KDIM][KPAD]            (2 MB)
//   [+14MB .. )    : partials f32 [BDIM]              (32 KB)

// Kernel 1: f32 -> bf16 convert (rows >= KDIM zero-padded).  [R11-verbatim]
__global__ __launch_bounds__(256) void k_convert(const float* __restrict__ W,
                                                 short* __restrict__ Wb){
  int gid  = blockIdx.x * 256 + threadIdx.x;
  int base = gid * 8;
  int row  = base >> 11;
  bf16x8 v;
  if (row < KDIM) {
    const float* src = W + base;
    #pragma unroll
    for (int i = 0; i < 8; i++) v[i] = (short)f2bf_rne(src[i]);
  } else {
    #pragma unroll
    for (int i = 0; i < 8; i++) v[i] = 0;
  }
  *(bf16x8*)(Wb + base) = v;
}

// Kernel 2: Gram, DOUBLE-BUFFERED LDS staging (2-phase pipeline), triangular,
// KSPLIT=2, in-block K-loop: 8 chunks of BK=128.
// LDS: As[2]/Bs[2] 64x128 bf16 panels (16 KB each, 64 KB total -> 2 blocks/CU).
// Per chunk: issue stage(next buf) BEFORE compute(cur buf); one barrier/chunk
// (its vmcnt drain makes next-buf ready and cur-buf reads complete).
// Swizzle: LDS slot s of row holds source cols ((s^(row&7))*8..+8); reads XOR
// identically -> ds_read_b128 16-way conflicts -> 2-way (free).
__global__ __launch_bounds__(256) void k_gram(const short* __restrict__ Wb,
                                              float* __restrict__ Gp){
  __shared__ short As[2][64 * 128];
  __shared__ short Bs[2][64 * 128];
  int tid = threadIdx.x, lane = tid & 63, w = tid >> 6;

  // decode triangular pair index -> (bx, by), bx<=by
  int t = blockIdx.x, bx = 0;
  while (t >= 16 - bx){ t -= 16 - bx; bx++; }
  int by = bx + t;
  int z  = blockIdx.y;
  const int ibase = bx * 64, jbase = by * 64;
  const bool diag = (bx == by);

  int r  = lane & 15, kg = lane >> 4;
  int ra = (w >> 1) * 32 + r;       // A local row ((ra+16)&7 == ra&7)
  int rb = (w & 1) * 32 + r;        // B local row

  f32x4 c00 = {0,0,0,0}, c01 = {0,0,0,0}, c10 = {0,0,0,0}, c11 = {0,0,0,0};

  // staging helper (macro-free): 1024 16B-slots per panel, 4 per thread.
  // slot_lin = c*256 + tid; row = slot_lin>>4; sl = slot_lin&15;
  // dest = panel + slot_lin*16B (wave-uniform base + lane*16 ✓)
  #define STAGE(bufidx, chunk)                                                  \
    {                                                                           \
      const int Kc_ = z * (DDIM / KSPLIT) + (chunk) * 128;                      \
      _Pragma("unroll")                                                         \
      for (int c = 0; c < 4; ++c){                                              \
        int sl_lin = c * 256 + tid;                                             \
        int row    = sl_lin >> 4, sl = sl_lin & 15;                             \
        int scol   = (sl ^ (row & 7)) * 8;                                      \
        gload16(Wb + (size_t)(ibase + row) * DDIM + Kc_ + scol,                 \
                &As[bufidx][sl_lin * 8]);                                       \
        if (!diag)                                                              \
          gload16(Wb + (size_t)(jbase + row) * DDIM + Kc_ + scol,               \
                  &Bs[bufidx][sl_lin * 8]);                                     \
      }                                                                         \
    }

  STAGE(0, 0);
  __syncthreads();                   // drains vmcnt -> buf0 ready

  for (int dc = 0; dc < 8; ++dc){
    int cur = dc & 1;
    if (dc < 7) STAGE(cur ^ 1, dc + 1);   // issue next-chunk loads (other buf)

    const short* Ap = As[cur];
    const short* Bp = diag ? As[cur] : Bs[cur];
    #pragma unroll
    for (int ds = 0; ds < 4; ++ds){
      int sa = ((ds * 4 + kg) ^ (ra & 7)) * 16;   // byte offset within 256B row
      int sb = ((ds * 4 + kg) ^ (rb & 7)) * 16;
      bf16x8 a0 = *(const bf16x8*)((const char*)Ap + ra * 256 + sa);
      bf16x8 a1 = *(const bf16x8*)((const char*)Ap + (ra + 16) * 256 + sa);
      bf16x8 b0 = *(const bf16x8*)((const char*)Bp + rb * 256 + sb);
      bf16x8 b1 = *(const bf16x8*)((const char*)Bp + (rb + 16) * 256 + sb);
      c00 = __builtin_amdgcn_mfma_f32_16x16x32_bf16(a0, b0, c00, 0, 0, 0);
      c01 = __builtin_amdgcn_mfma_f32_16x16x32_bf16(a0, b1, c01, 0, 0, 0);
      c10 = __builtin_amdgcn_mfma_f32_16x16x32_bf16(a1, b0, c10, 0, 0, 0);
      c11 = __builtin_amdgcn_mfma_f32_16x16x32_bf16(a1, b1, c11, 0, 0, 0);
    }
    __syncthreads();                 // next-buf staged + cur-buf reads done
  }
  #undef STAGE

  // ---- C write. D layout: col = lane&15, row = (lane>>4)*4 + reg [m89]
  int orow = (lane >> 4) * 4, ocol = lane & 15;
  int i0 = ibase + (w >> 1) * 32, j0 = jbase + (w & 1) * 32;
  float* Gz = Gp + ((size_t)z << 20);
  float* g  = Gz + (size_t)(i0 + orow) * KPAD + (j0 + ocol);
  #pragma unroll
  for (int rr = 0; rr < 4; rr++){
    g[(size_t)rr * KPAD]             = c00[rr];
    g[(size_t)rr * KPAD + 16]        = c01[rr];
    g[(size_t)(rr + 16) * KPAD]      = c10[rr];
    g[(size_t)(rr + 16) * KPAD + 16] = c11[rr];
  }
  if (!diag){      // transposed tile (lower triangle); contiguous f32x4 stores
    float* gt = Gz + (size_t)(j0 + ocol) * KPAD + (i0 + orow);
    *(f32x4*)gt                            = c00;
    *(f32x4*)(gt + 16)                     = c10;
    *(f32x4*)(gt + (size_t)16 * KPAD)      = c01;
    *(f32x4*)(gt + (size_t)16 * KPAD + 16) = c11;
  }
}

// Kernel 3: TSb[l,:] = bf16(softmax(relu(sum_z Gp[z][l,:])^0.3 / 0.3)). [R11-verbatim]
__global__ __launch_bounds__(256) void k_ts(const float* __restrict__ Gp,
                                            unsigned short* __restrict__ TSb){
  int l = blockIdx.x;
  int t = threadIdx.x;
  int lane = t & 63, w = t >> 6;
  f32x4 g = *((const f32x4*)(Gp + (size_t)l * KPAD) + t)
          + *((const f32x4*)(Gp + (1ull << 20) + (size_t)l * KPAD) + t);
  f32x4 e;
  float s = 0.f;
  #pragma unroll
  for (int c = 0; c < 4; c++){
    int k = t * 4 + c;
    float gg = g[c];
    float zv = (gg > 0.f) ? __expf(0.3f * __logf(gg)) * (1.0f / 0.3f) : 0.f;
    float ee = (k < KDIM) ? __expf(zv) : 0.f;   // zv in [0,~34] -> exp <= 3.5e14
    e[c] = ee;
    s += ee;
  }
  s = wred_sum(s);
  __shared__ float ps[4];
  if (lane == 0) ps[w] = s;
  __syncthreads();
  float inv = 1.0f / (ps[0] + ps[1] + ps[2] + ps[3]);
  u16x4 o;
  #pragma unroll
  for (int c = 0; c < 4; c++) o[c] = f2bf_rne(e[c] * inv);
  *(u16x4*)(TSb + (size_t)l * KPAD + t * 4) = o;
}

// Kernel 4: per-row loss, 2 waves per row, LDS combine. [R11-verbatim, single-pass]
__global__ __launch_bounds__(256) void k_loss(const float* __restrict__ pred,
                                              const float* __restrict__ teacher,
                                              const int* __restrict__ label,
                                              const unsigned short* __restrict__ TSb,
                                              float* __restrict__ partials){
  int tid = threadIdx.x;
  int lane = tid & 63;
  int wv   = tid >> 6;            // 0..3
  int rib  = wv >> 1;             // row in block: 0,1
  int h    = wv & 1;              // half: 0,1
  int b = blockIdx.x * 2 + rib;
  int l = label[b];
  const int base4 = h * 125;
  const u16x4* tsr = (const u16x4*)(TSb + (size_t)l * KPAD) + base4;
  const f32x4* pr  = (const f32x4*)(pred    + (size_t)b * KDIM) + base4;
  const f32x4* th  = (const f32x4*)(teacher + (size_t)b * KDIM) + base4;

  u16x4 ts[2];
  f32x4 x[2], y[2];
  #pragma unroll
  for (int j = 0; j < 2; j++){
    int idx = lane + 64 * j;           // 0..127, valid < 125
    bool v = (idx < 125);
    f32x4 neg = {-4e30f, -4e30f, -4e30f, -4e30f};
    ts[j]   = v ? tsr[idx] : (u16x4){0,0,0,0};
    f32x4 p = v ? pr[idx]  : neg;
    f32x4 t = v ? th[idx]  : neg;
    x[j] = p * TINV;
    y[j] = t * TINV;
  }
  float sp = 0.f, st = 0.f;
  #pragma unroll
  for (int j = 0; j < 2; j++)
    #pragma unroll
    for (int c = 0; c < 4; c++){
      sp += __expf(x[j][c]);           // sentinel lanes: exp(-1e30)=0
      st += __expf(y[j][c]);
    }
  sp = wred_sum(sp); st = wred_sum(st);

  __shared__ float s_sp[4], s_st[4], s_yl[2], s_S[4];
  if (lane == 0){ s_sp[wv] = sp; s_st[wv] = st; }
  int l4 = l >> 2;
  if (l4 >= base4 && l4 < base4 + 125){
    int rel = l4 - base4;
    int jl = rel >> 6, lanel = rel & 63, cl = l & 3;
    f32x4 yj   = jl ? y[1] : y[0];
    float cand = (cl == 0) ? yj[0] : (cl == 1) ? yj[1] : (cl == 2) ? yj[2] : yj[3];
    float yl   = __shfl(cand, lanel, 64);
    if (lane == 0) s_yl[rib] = yl;
  }
  __syncthreads();
  float spF = s_sp[rib * 2] + s_sp[rib * 2 + 1];
  float stF = s_st[rib * 2] + s_st[rib * 2 + 1];
  float lse_p = __logf(spF);
  float lse_t = __logf(stF);
  float conf  = __expf(s_yl[rib] - lse_t);
  float u = (1.f - conf) * (1.f / 999.f);

  float S = 0.f;
  #pragma unroll
  for (int j = 0; j < 2; j++){
    int idx = lane + 64 * j;
    if (idx < 125){
      #pragma unroll
      for (int c = 0; c < 4; c++){
        int k = (base4 + idx) * 4 + c;
        float t = 0.5f * (((k == l) ? conf : u) + bf2f(ts[j][c]));
        S += t * (__logf(t) - x[j][c]);
      }
    }
  }
  S = wred_sum(S);
  if (lane == 0) s_S[wv] = S;
  __syncthreads();
  if (h == 0 && lane == 0)
    partials[b] = s_S[rib * 2] + s_S[rib * 2 + 1] + lse_p;  // sum(target)=1 -> +lse_p
}

// Kernel 5: reduce 8192 partials, scale. 1 block, 256 threads. [R11-verbatim]
__global__ __launch_bounds__(256) void k_fin(const float* __restrict__ partials,
                                             float* __restrict__ out){
  int t = threadIdx.x;
  float s = 0.f;
  #pragma unroll 8
  for (int i = t; i < BDIM; i += 256) s += partials[i];
  s = wred_sum(s);
  __shared__ float ps[4];
  if ((t & 63) == 0) ps[t >> 6] = s;
  __syncthreads();
  if (t == 0) out[0] = (ps[0] + ps[1] + ps[2] + ps[3]) * (16.0f / 8192.0f);
}

extern "C" void kernel_launch(void* const* d_in, const int* in_sizes, int n_in,
                              void* d_out, int out_size, void* d_ws, size_t ws_size,
                              hipStream_t stream) {
  const float* pred    = (const float*)d_in[0];
  const float* teacher = (const float*)d_in[1];
  const float* weight  = (const float*)d_in[2];
  const int*   label   = (const int*)d_in[3];
  float* out = (float*)d_out;

  char* ws = (char*)d_ws;
  short*          Wb       = (short*)(ws + 256);
  float*          Gp       = (float*)(ws + 256 + (size_t)KPAD * DDIM * 2);
  unsigned short* TSb      = (unsigned short*)(ws + 256 + (size_t)KPAD * DDIM * 2
                                                  + (size_t)KSPLIT * KPAD * KPAD * 4);
  float*          partials = (float*)((char*)TSb + (size_t)KDIM * KPAD * 2);

  k_convert<<<dim3((KPAD * DDIM / 8) / 256), dim3(256), 0, stream>>>(weight, Wb);
  k_gram<<<dim3(136, KSPLIT), dim3(256), 0, stream>>>(Wb, Gp);
  k_ts<<<dim3(KDIM), dim3(256), 0, stream>>>(Gp, TSb);
  k_loss<<<dim3(BDIM / 2), dim3(256), 0, stream>>>(pred, teacher, label, TSb, partials);
  k_fin<<<dim3(1), dim3(256), 0, stream>>>(partials, out);
}